// Round 3
// baseline (312.344 us; speedup 1.0000x reference)
//
#include <hip/hip_runtime.h>

#define Wd 1024
#define Hd 1024
#define SH 16            // output rows per block
#define ITER (SH + 6)    // input rows streamed (3-row halo each side)

__global__ __launch_bounds__(256, 4)
void lvm_wave(const float* __restrict__ x, float* __restrict__ out) {
    const int b    = blockIdx.y;
    const int row0 = blockIdx.x * SH;
    const int tid  = threadIdx.x;
    const int c0   = tid * 4;        // this thread's 4 output columns
    const int lane = tid & 63;

    const float* x0 = x + (size_t)b * 3 * Hd * Wd;
    const float* x1 = x0 + (size_t)Hd * Wd;
    const float* x2 = x1 + (size_t)Hd * Wd;
    float*       ob = out + (size_t)b * Hd * Wd;

    float4 ring1[7], ring2[7];                   // last 7 rows' horizontal sums
    float4 t1 = make_float4(0.f, 0.f, 0.f, 0.f); // running vertical totals
    float4 t2 = make_float4(0.f, 0.f, 0.f, 0.f);

#pragma unroll
    for (int i = 0; i < ITER; ++i) {
        const int ri = row0 - 3 + i;             // input row (wave-uniform)
        float4 lum4 = make_float4(0.f, 0.f, 0.f, 0.f);
        float lm1 = 0.f, lm2 = 0.f, lm3 = 0.f;   // lum[c0-3..c0-1]
        float lp4 = 0.f, lp5 = 0.f, lp6 = 0.f;   // lum[c0+4..c0+6]

        if (ri >= 0 && ri < Hd) {                // wave-uniform branch
            const size_t o = (size_t)ri * Wd + c0;
            float4 a = *(const float4*)(x0 + o);
            float4 g = *(const float4*)(x1 + o);
            float4 c = *(const float4*)(x2 + o);
            lum4.x = (a.x + g.x + c.x) * (1.f / 3.f);
            lum4.y = (a.y + g.y + c.y) * (1.f / 3.f);
            lum4.z = (a.z + g.z + c.z) * (1.f / 3.f);
            lum4.w = (a.w + g.w + c.w) * (1.f / 3.f);

            // horizontal halo from neighbor lanes (wave = 256 contiguous cols)
            lm1 = __shfl_up(lum4.y, 1);
            lm2 = __shfl_up(lum4.z, 1);
            lm3 = __shfl_up(lum4.w, 1);
            lp4 = __shfl_down(lum4.x, 1);
            lp5 = __shfl_down(lum4.y, 1);
            lp6 = __shfl_down(lum4.z, 1);

            // wave-edge lanes fetch their halo directly (exec-masked, 2/64 lanes)
            if (lane == 0) {
                if (c0 >= 4) {
                    float4 a2 = *(const float4*)(x0 + o - 4);
                    float4 g2 = *(const float4*)(x1 + o - 4);
                    float4 c2 = *(const float4*)(x2 + o - 4);
                    lm1 = (a2.y + g2.y + c2.y) * (1.f / 3.f);
                    lm2 = (a2.z + g2.z + c2.z) * (1.f / 3.f);
                    lm3 = (a2.w + g2.w + c2.w) * (1.f / 3.f);
                } else {                         // true left image edge: zero pad
                    lm1 = lm2 = lm3 = 0.f;
                }
            }
            if (lane == 63) {
                if (c0 + 4 < Wd) {
                    float4 a2 = *(const float4*)(x0 + o + 4);
                    float4 g2 = *(const float4*)(x1 + o + 4);
                    float4 c2 = *(const float4*)(x2 + o + 4);
                    lp4 = (a2.x + g2.x + c2.x) * (1.f / 3.f);
                    lp5 = (a2.y + g2.y + c2.y) * (1.f / 3.f);
                    lp6 = (a2.z + g2.z + c2.z) * (1.f / 3.f);
                } else {                         // true right image edge
                    lp4 = lp5 = lp6 = 0.f;
                }
            }
        }

        // window v1..v10 = lum[c0-3 .. c0+6]
        const float v1 = lm1, v2 = lm2, v3 = lm3;
        const float v4 = lum4.x, v5 = lum4.y, v6 = lum4.z, v7 = lum4.w;
        const float v8 = lp4, v9 = lp5, v10 = lp6;

        // horizontal 7-tap sums, sliding across the 4 output columns
        float s1a = v1 + v2 + v3 + v4 + v5 + v6 + v7;
        float s1b = s1a - v1 + v8;
        float s1c = s1b - v2 + v9;
        float s1d = s1c - v3 + v10;

        float q1 = v1*v1, q2 = v2*v2, q3 = v3*v3, q4 = v4*v4, q5 = v5*v5;
        float q6 = v6*v6, q7 = v7*v7, q8 = v8*v8, q9 = v9*v9, q10 = v10*v10;
        float s2a = q1 + q2 + q3 + q4 + q5 + q6 + q7;
        float s2b = s2a - q1 + q8;
        float s2c = s2b - q2 + q9;
        float s2d = s2c - q3 + q10;

        float4 s1 = make_float4(s1a, s1b, s1c, s1d);
        float4 s2 = make_float4(s2a, s2b, s2c, s2d);

        // running vertical total: add new row, subtract row i-7
        t1.x += s1.x; t1.y += s1.y; t1.z += s1.z; t1.w += s1.w;
        t2.x += s2.x; t2.y += s2.y; t2.z += s2.z; t2.w += s2.w;
        if (i >= 7) {
            float4 o1 = ring1[i % 7], o2 = ring2[i % 7];
            t1.x -= o1.x; t1.y -= o1.y; t1.z -= o1.z; t1.w -= o1.w;
            t2.x -= o2.x; t2.y -= o2.y; t2.z -= o2.z; t2.w -= o2.w;
        }
        ring1[i % 7] = s1;
        ring2[i % 7] = s2;

        if (i >= 6) {                            // emit output row row0+i-6
            const float inv = 1.f / 49.f;
            float mx = t1.x * inv, my = t1.y * inv, mz = t1.z * inv, mw = t1.w * inv;
            float4 r;
            r.x = t2.x * inv - mx * mx;
            r.y = t2.y * inv - my * my;
            r.z = t2.z * inv - mz * mz;
            r.w = t2.w * inv - mw * mw;
            const int ro = row0 + i - 6;
            *(float4*)(ob + (size_t)ro * Wd + c0) = r;
        }
    }
}

extern "C" void kernel_launch(void* const* d_in, const int* in_sizes, int n_in,
                              void* d_out, int out_size, void* d_ws, size_t ws_size,
                              hipStream_t stream) {
    const float* x = (const float*)d_in[0];
    float* out = (float*)d_out;
    dim3 grid(Hd / SH, 16);   // 64 row-strips x 16 batches = 1024 blocks
    lvm_wave<<<grid, dim3(256), 0, stream>>>(x, out);
}